// Round 3
// baseline (269.124 us; speedup 1.0000x reference)
//
#include <hip/hip_runtime.h>

typedef __attribute__((ext_vector_type(8))) short short8;
typedef __attribute__((ext_vector_type(4))) float f32x4;
typedef __attribute__((ext_vector_type(16))) float f32x16;
typedef unsigned short u16;
typedef unsigned int u32;

#define NB_TOT 8192
#define DIM 192

// ws byte offsets (prep outputs only)
#define WN_OFF    0          // [576][192] bf16 qkv_w (n-major)
#define WCN_OFF   221184     // [192][192] bf16 nn1_w@attn_w (n-major)
#define BC_OFF    294912     // [192] f32
#define KRELF_OFF 295680     // [17][4][64][8] bf16 rel B-frags
#define MPA_OFF   365312     // [289] f32 mask*PA

// fused LDS (u16 units), block = 2 batches (34 rows, 6 bh), 512 threads (8 waves)
// 52.0 KiB alloc (52,864 B -> 53,248) => 3 blocks/CU with 4 KiB headroom:
//   XS @ 0     : x[34][200] bf16 (GEMM A-rows >=34 read in-bounds garbage, discarded)
//                overlay1: Sf f32[6*289] (born at QK^T store, dead after softmax)
//                overlay2: ao [34][200]  (born at PV, read by out-proj)
//   K  @ 6800  : k slots [bh][17][64] XOR-swizzled (col ^ ((row&7)<<3)), stride 1088
//                overlay: wbf u16[102*32] + dropl f32[102] (after QK^T, k dead)
//   V  @ 13328 : v slots [bh][17][64] plain, stride 1088
//   Q  @ 19856 : q slots [bh][17][64] XOR-swizzled, stride 1096 (8-u16 inter-slot
//                pad: rel reads cross slots per-lane; 1088*2B is bank-stride 0)
#define XS_O 0
#define K_O  6800
#define V_O  13328
#define Q_O  19856
#define SMEM_U16 26432

__device__ __forceinline__ u16 f2b(float f) {
  u32 u = __float_as_uint(f);
  u32 r = u + 0x7FFFu + ((u >> 16) & 1u);  // RNE
  return (u16)(r >> 16);
}

// LDS-only barrier (global ops have register data-deps; final stores need no drain)
__device__ __forceinline__ void bar_lgkm() {
  asm volatile("s_waitcnt lgkmcnt(0)" ::: "memory");
  __builtin_amdgcn_s_barrier();
  asm volatile("" ::: "memory");
}

__global__ void prep_kernel(const float* __restrict__ qkv_w,
                            const float* __restrict__ attn_w,
                            const float* __restrict__ attn_b,
                            const float* __restrict__ nn1_w,
                            const float* __restrict__ nn1_b,
                            const float* __restrict__ key_rel,
                            const float* __restrict__ krd,
                            const float* __restrict__ mask,
                            const float* __restrict__ PA,
                            char* __restrict__ ws) {
  u16* wN    = (u16*)(ws + WN_OFF);
  u16* wcN   = (u16*)(ws + WCN_OFF);
  float* bc  = (float*)(ws + BC_OFF);
  u16* krelf = (u16*)(ws + KRELF_OFF);
  float* mpa = (float*)(ws + MPA_OFF);
  for (int idx = blockIdx.x * 256 + threadIdx.x; idx < 152289; idx += gridDim.x * 256) {
    if (idx < 110592) {
      wN[idx] = f2b(qkv_w[idx]);
    } else if (idx < 147456) {
      int t2 = idx - 110592; int n = t2 / 192, k = t2 - n * 192;
      float a = 0.f;
      for (int t = 0; t < 192; ++t) a = fmaf(nn1_w[n * 192 + t], attn_w[t * 192 + k], a);
      wcN[n * 192 + k] = f2b(a);
    } else if (idx < 147648) {
      int n = idx - 147456; float a = nn1_b[n];
      for (int t = 0; t < 192; ++t) a = fmaf(nn1_w[n * 192 + t], attn_b[t], a);
      bc[n] = a;
    } else if (idx < 152000) {
      int t = idx - 147648;              // ((I*4+ks)*64 + lane)
      int lane = t & 63, ks = (t >> 6) & 3, I = t >> 8;
      int J = lane & 31;
      int d0 = ks * 16 + (lane >> 5) * 8;
      u16 vals[8];
#pragma unroll
      for (int i = 0; i < 8; ++i) {
        float v = 0.f;
        if (J <= 16) {
          if (J == I) v = krd[d0 + i];
          else { int tt = 17 * I + J; int p = tt - tt / 18 - 1; v = key_rel[p * 64 + d0 + i]; }
        }
        vals[i] = f2b(v);
      }
      u32 w0 = vals[0] | ((u32)vals[1] << 16), w1 = vals[2] | ((u32)vals[3] << 16);
      u32 w2 = vals[4] | ((u32)vals[5] << 16), w3 = vals[6] | ((u32)vals[7] << 16);
      uint4 pk; pk.x = w0; pk.y = w1; pk.z = w2; pk.w = w3;
      *(uint4*)(krelf + (size_t)t * 8) = pk;
    } else {
      int i = idx - 152000; mpa[i] = mask[i] * PA[i];
    }
  }
}

// ---------------- fused v5: 2 batches/block, 8 waves, 3 blocks/CU, 6 barriers ----------------
__global__ __launch_bounds__(512, 6)
void fused_kernel(const float* __restrict__ x, const float* __restrict__ gm,
                  const float* __restrict__ drop, const float* __restrict__ qkv_b,
                  const u16* __restrict__ wN, const u16* __restrict__ wcN,
                  const float* __restrict__ bc, const u16* __restrict__ krelf,
                  const float* __restrict__ mpa, float* __restrict__ out) {
  __shared__ u16 smem[SMEM_U16];
  float* const Sf    = (float*)(smem + XS_O);        // 6*289 f32 overlay (after GEMM)
  u16*   const wbf   = smem + K_O;                   // 102*32 u16 overlay (after QK^T)
  float* const dropl = (float*)(smem + K_O + 3264);  // 102 f32 overlay (after QK^T)

  const int tid = threadIdx.x;
  const int blk = blockIdx.x;
  const int lane = tid & 63;
  const int l31 = lane & 31;
  const int lh = lane >> 5;
  const int wv = tid >> 6;

  // ---- prefetch: drop (1 reg) + gm C-fragments (16 regs, QK^T C-init layout) ----
  float drv = 0.f;
  if (tid < 102) drv = drop[(size_t)blk * 102 + tid];
  float gm16[16];
  {
    const float* gmw = gm + (size_t)blk * 1734 + wv * 289;
#pragma unroll
    for (int g = 0; g < 16; ++g) {
      int I = (g & 3) + 8 * (g >> 2) + 4 * lh;
      gm16[g] = (wv < 6 && I < 17 && l31 < 17) ? gmw[I * 17 + l31] : 0.f;
    }
  }

  // ---- stage x -> LDS bf16 [34][200] ----
  const float* xb = x + (size_t)blk * 34 * 192;
  for (int idx = tid; idx < 1632; idx += 512) {
    int row = idx / 48, k4 = (idx - row * 48) * 4;
    float4 v = *(const float4*)(xb + row * 192 + k4);
    u16 p[4] = {f2b(v.x), f2b(v.y), f2b(v.z), f2b(v.w)};
    *(uint2*)(smem + XS_O + row * 200 + k4) = *(uint2*)p;
  }
  bar_lgkm();

  const int lrow = tid & 15, lg = (tid >> 4) & 3, kgrp = lg * 8;

  // ---- qkv GEMM: 36 N-tiles of 16 cols across 8 waves; B-frags reg-resident,
  //      reused over 3 M-tiles; no barriers. A-rows >=34 are garbage -> discarded ----
  for (int N = wv; N < 36; N += 8) {
    const int c0 = N * 16;
    const int which = c0 / 192;
    const int hd = c0 - which * 192;
    const int h = hd >> 6;
    const int d = (hd & 63) + lrow;
    const int c = c0 + lrow;
    const u16* wB = wN + (size_t)c * 192;
    short8 bfr[6];
#pragma unroll
    for (int kk = 0; kk < 6; ++kk)
      bfr[kk] = *(const short8*)(wB + kk * 32 + kgrp);
    const float bias = qkv_b[c];
    const float scale = which ? 1.0f : 0.125f;
#pragma unroll
    for (int m = 0; m < 3; ++m) {
      f32x4 acc = {};
#pragma unroll
      for (int kk = 0; kk < 6; ++kk) {
        short8 a = *(const short8*)(smem + XS_O + (m * 16 + lrow) * 200 + kk * 32 + kgrp);
        acc = __builtin_amdgcn_mfma_f32_16x16x32_bf16(a, bfr[kk], acc, 0, 0, 0);
      }
#pragma unroll
      for (int j = 0; j < 4; ++j) {
        int r = m * 16 + lg * 4 + j;
        if (r < 34) {
          int bi = r >= 17 ? 1 : 0, I = r - bi * 17;
          int slot = bi * 3 + h;
          u16 val = f2b((acc[j] + bias) * scale);
          if (which == 0)      smem[Q_O + slot * 1096 + I * 64 + (d ^ ((I & 7) << 3))] = val;
          else if (which == 1) smem[K_O + slot * 1088 + I * 64 + (d ^ ((I & 7) << 3))] = val;
          else                 smem[V_O + slot * 1088 + I * 64 + d] = val;
        }
      }
    }
  }
  bar_lgkm();   // q/k/v complete; x dead -> Sf may overlay

  const int rowc = l31 < 16 ? l31 : 16;

  // ---- QK^T; C-init = prefetched gm; STORES Sf (S-init phase eliminated) ----
  if (wv < 6) {
    int bh = wv;
    const u16* qb = smem + Q_O + bh * 1096;
    const u16* kb = smem + K_O + bh * 1088;
    const int swr = (rowc & 7) << 3;
    f32x16 acc;
#pragma unroll
    for (int g = 0; g < 16; ++g) acc[g] = gm16[g];
#pragma unroll
    for (int ks = 0; ks < 4; ++ks) {
      int off = (ks * 16 + lh * 8) ^ swr;
      short8 afr = *(const short8*)(qb + rowc * 64 + off);
      short8 bfr = *(const short8*)(kb + rowc * 64 + off);
      acc = __builtin_amdgcn_mfma_f32_32x32x16_bf16(afr, bfr, acc, 0, 0, 0);
    }
    if (l31 < 17) {
      float* Sb = Sf + bh * 289 + l31;
#pragma unroll
      for (int g = 0; g < 16; ++g) {
        int I = (g & 3) + 8 * (g >> 2) + 4 * lh;
        if (I < 17) Sb[I * 17] = acc[g];
      }
    }
  }
  bar_lgkm();   // k dead -> wbf/dropl may overlay

  // ---- rel logits (adds into S, + mpa once per element); park dropl in dead-K ----
  for (int I = wv; I < 17; I += 8) {
    int bhA = l31 < 6 ? l31 : 5;
    const u16* qb = smem + Q_O + bhA * 1096 + I * 64;
    const int swz = (I & 7) << 3;
    float mpav = (l31 < 17) ? mpa[I * 17 + l31] : 0.f;
    f32x16 acc = {};
#pragma unroll
    for (int ks = 0; ks < 4; ++ks) {
      short8 afr = *(const short8*)(qb + ((ks * 16 + lh * 8) ^ swz));
      short8 bfr = *(const short8*)(krelf + ((size_t)(I * 4 + ks) * 64 + lane) * 8);
      acc = __builtin_amdgcn_mfma_f32_32x32x16_bf16(afr, bfr, acc, 0, 0, 0);
    }
    if (l31 < 17) {
#pragma unroll
      for (int g = 0; g < 16; ++g) {
        int bh = (g & 3) + 8 * (g >> 2) + 4 * lh;
        if (bh < 6) Sf[bh * 289 + I * 17 + l31] += acc[g] + mpav;
      }
    }
  }
  if (tid < 102) dropl[tid] = drv;
  bar_lgkm();

  // ---- softmax + dropout renorm -> wbf (bf16, swizzled; overlays dead k) ----
  if (tid < 102) {
    int bh = tid / 17, I = tid - bh * 17;
    float* row = Sf + bh * 289 + I * 17;
    float lv[17];
#pragma unroll
    for (int J = 0; J < 17; ++J) lv[J] = row[J];
    float m = lv[0];
#pragma unroll
    for (int J = 1; J < 17; ++J) m = fmaxf(m, lv[J]);
    float s1 = 0.f;
#pragma unroll
    for (int J = 0; J < 17; ++J) { lv[J] = __expf(lv[J] - m); s1 += lv[J]; }
    const float* dr = dropl + bh * 17;
    float inv1 = 1.0f / s1, s2 = 0.f;
#pragma unroll
    for (int J = 0; J < 17; ++J) { float w2 = lv[J] * inv1 * dr[J]; lv[J] = w2; s2 += w2; }
    float inv2 = 1.0f / (s2 + 1e-8f);
    u32* wr32 = (u32*)(wbf + (bh * 17 + I) * 32);
    int sw = (I & 3) << 2;
#pragma unroll
    for (int k2 = 0; k2 < 16; ++k2) {
      u16 lo = (2 * k2 < 17) ? f2b(lv[2 * k2] * inv2) : (u16)0;
      u16 hi = (2 * k2 + 1 < 17) ? f2b(lv[2 * k2 + 1] * inv2) : (u16)0;
      wr32[k2 ^ sw] = lo | ((u32)hi << 16);
    }
  }
  bar_lgkm();

  // ---- PV -> ao (overlays dead Sf at XS_O, [34][200]); nt-tiles SERIALIZED
  //      (one f32x16 live -> lower reg peak); v frags via ds_read_u16 ----
  if (wv < 6) {
    int bh = wv;
    const u16* wb = wbf + (bh * 17 + rowc) * 32;
    int sw = (rowc & 3) << 3;   // u16 units
    short8 wa0 = *(const short8*)(wb + ((lh * 8) ^ sw));
    short8 wa1 = *(const short8*)(wb + ((lh * 8 + 16) ^ sw));
    int bi = bh >= 3 ? 1 : 0, h = bh - bi * 3;
    const u16* vb = smem + V_O + bh * 1088;
#pragma unroll
    for (int nt = 0; nt < 2; ++nt) {
      int d = nt * 32 + l31;
      short8 v0;
#pragma unroll
      for (int i = 0; i < 8; ++i) v0[i] = (short)vb[(lh * 8 + i) * 64 + d];
      f32x16 acc = {};
      acc = __builtin_amdgcn_mfma_f32_32x32x16_bf16(wa0, v0, acc, 0, 0, 0);
      short8 v1 = {};
      if (lh == 0) v1[0] = (short)vb[16 * 64 + d];
      acc = __builtin_amdgcn_mfma_f32_32x32x16_bf16(wa1, v1, acc, 0, 0, 0);
#pragma unroll
      for (int g = 0; g < 16; ++g) {
        int I = (g & 3) + 8 * (g >> 2) + 4 * lh;
        if (I < 17) smem[XS_O + (bi * 17 + I) * 200 + h * 64 + d] = f2b(acc[g]);
      }
    }
  }
  bar_lgkm();

  // ---- out-proj: 12 n-tiles across 8 waves; B-frags reg-resident over 3 M-tiles.
  //      A = ao at XS_O; rows >=34 read in-bounds garbage -> discarded ----
  float* outb = out + (size_t)blk * 34 * 192;
  for (int n = wv; n < 12; n += 8) {
    const int nc = n * 16 + lrow;
    short8 bfr[6];
#pragma unroll
    for (int kk = 0; kk < 6; ++kk)
      bfr[kk] = *(const short8*)(wcN + (size_t)nc * 192 + kk * 32 + kgrp);
    const float bias = bc[nc];
#pragma unroll
    for (int m = 0; m < 3; ++m) {
      f32x4 acc = {};
#pragma unroll
      for (int kk = 0; kk < 6; ++kk) {
        short8 a = *(const short8*)(smem + XS_O + (m * 16 + lrow) * 200 + kk * 32 + kgrp);
        acc = __builtin_amdgcn_mfma_f32_16x16x32_bf16(a, bfr[kk], acc, 0, 0, 0);
      }
#pragma unroll
      for (int j = 0; j < 4; ++j) {
        int r = m * 16 + lg * 4 + j;
        if (r < 34) outb[(size_t)r * 192 + nc] = acc[j] + bias;
      }
    }
  }
}

extern "C" void kernel_launch(void* const* d_in, const int* in_sizes, int n_in,
                              void* d_out, int out_size, void* d_ws, size_t ws_size,
                              hipStream_t stream) {
  const float* x    = (const float*)d_in[0];
  const float* mask = (const float*)d_in[1];
  const float* gm   = (const float*)d_in[2];
  const float* drop = (const float*)d_in[3];
  const float* qkvw = (const float*)d_in[4];
  const float* qkvb = (const float*)d_in[5];
  const float* attw = (const float*)d_in[6];
  const float* attb = (const float*)d_in[7];
  const float* krel = (const float*)d_in[8];
  const float* krd  = (const float*)d_in[9];
  const float* PA   = (const float*)d_in[10];
  const float* nn1w = (const float*)d_in[11];
  const float* nn1b = (const float*)d_in[12];
  char* ws = (char*)d_ws;
  float* out = (float*)d_out;

  prep_kernel<<<600, 256, 0, stream>>>(qkvw, attw, attb, nn1w, nn1b, krel, krd, mask, PA, ws);

  const u16* wN    = (const u16*)(ws + WN_OFF);
  const u16* wcN   = (const u16*)(ws + WCN_OFF);
  const float* bc  = (const float*)(ws + BC_OFF);
  const u16* krelf = (const u16*)(ws + KRELF_OFF);
  const float* mpa = (const float*)(ws + MPA_OFF);

  fused_kernel<<<NB_TOT / 2, 512, 0, stream>>>(x, gm, drop, qkvb, wN, wcN, bc, krelf, mpa, out);
}

// Round 4
// 188.114 us; speedup vs baseline: 1.4306x; 1.4306x over previous
//
#include <hip/hip_runtime.h>

typedef __attribute__((ext_vector_type(8))) short short8;
typedef __attribute__((ext_vector_type(4))) float f32x4;
typedef __attribute__((ext_vector_type(16))) float f32x16;
typedef unsigned short u16;
typedef unsigned int u32;

#define NB_TOT 8192
#define DIM 192

// ws byte offsets (prep outputs only)
#define WN_OFF    0          // [576][192] bf16 qkv_w (n-major)
#define WCN_OFF   221184     // [192][192] bf16 nn1_w@attn_w (n-major)
#define BC_OFF    294912     // [192] f32
#define KRELF_OFF 295680     // [17][4][64][8] bf16 rel B-frags
#define MPA_OFF   365312     // [289] f32 mask*PA

// fused LDS (u16 units), block = 2 batches (34 rows, 6 bh), 512 threads (8 waves)
// 60,224 B -> alloc 60,416; x2 = 120,832 <= 160 KiB => 2 blocks/CU:
//   XS  @ 0     : x[34][200] bf16 (GEMM A-rows >=34 read in-bounds garbage, discarded)
//                 overlay1: Sf f32[1734] (QK^T output, dead after softmax)
//                 overlay2: ao [34][200] (born at PV, read by out-proj)
//   SF2 @ 6800  : f32[1734] rel+mpa accumulator (written in merged phase)
//   K   @ 10272 : k slots [bh][17][64] XOR-swizzled (col ^ ((row&7)<<3)), stride 1088
//                 overlay: wbf u16[102*32] (born at softmax; k dead after merged phase)
//   V   @ 16800 : v slots [bh][17][64] plain, stride 1088
//   Q   @ 23328 : q slots [bh][17][64] XOR-swizzled, stride 1096 (8-u16 inter-slot pad)
//   DR  @ 29904 : dropl f32[102]
#define XS_O  0
#define SF2_O 6800
#define K_O   10272
#define V_O   16800
#define Q_O   23328
#define DR_O  29904
#define SMEM_U16 30112

__device__ __forceinline__ u16 f2b(float f) {
  u32 u = __float_as_uint(f);
  u32 r = u + 0x7FFFu + ((u >> 16) & 1u);  // RNE
  return (u16)(r >> 16);
}

// LDS-only barrier (global ops have register data-deps; final stores need no drain)
__device__ __forceinline__ void bar_lgkm() {
  asm volatile("s_waitcnt lgkmcnt(0)" ::: "memory");
  __builtin_amdgcn_s_barrier();
  asm volatile("" ::: "memory");
}

__global__ void prep_kernel(const float* __restrict__ qkv_w,
                            const float* __restrict__ attn_w,
                            const float* __restrict__ attn_b,
                            const float* __restrict__ nn1_w,
                            const float* __restrict__ nn1_b,
                            const float* __restrict__ key_rel,
                            const float* __restrict__ krd,
                            const float* __restrict__ mask,
                            const float* __restrict__ PA,
                            char* __restrict__ ws) {
  u16* wN    = (u16*)(ws + WN_OFF);
  u16* wcN   = (u16*)(ws + WCN_OFF);
  float* bc  = (float*)(ws + BC_OFF);
  u16* krelf = (u16*)(ws + KRELF_OFF);
  float* mpa = (float*)(ws + MPA_OFF);
  for (int idx = blockIdx.x * 256 + threadIdx.x; idx < 152289; idx += gridDim.x * 256) {
    if (idx < 110592) {
      wN[idx] = f2b(qkv_w[idx]);
    } else if (idx < 147456) {
      int t2 = idx - 110592; int n = t2 / 192, k = t2 - n * 192;
      float a = 0.f;
      for (int t = 0; t < 192; ++t) a = fmaf(nn1_w[n * 192 + t], attn_w[t * 192 + k], a);
      wcN[n * 192 + k] = f2b(a);
    } else if (idx < 147648) {
      int n = idx - 147456; float a = nn1_b[n];
      for (int t = 0; t < 192; ++t) a = fmaf(nn1_w[n * 192 + t], attn_b[t], a);
      bc[n] = a;
    } else if (idx < 152000) {
      int t = idx - 147648;              // ((I*4+ks)*64 + lane)
      int lane = t & 63, ks = (t >> 6) & 3, I = t >> 8;
      int J = lane & 31;
      int d0 = ks * 16 + (lane >> 5) * 8;
      u16 vals[8];
#pragma unroll
      for (int i = 0; i < 8; ++i) {
        float v = 0.f;
        if (J <= 16) {
          if (J == I) v = krd[d0 + i];
          else { int tt = 17 * I + J; int p = tt - tt / 18 - 1; v = key_rel[p * 64 + d0 + i]; }
        }
        vals[i] = f2b(v);
      }
      u32 w0 = vals[0] | ((u32)vals[1] << 16), w1 = vals[2] | ((u32)vals[3] << 16);
      u32 w2 = vals[4] | ((u32)vals[5] << 16), w3 = vals[6] | ((u32)vals[7] << 16);
      uint4 pk; pk.x = w0; pk.y = w1; pk.z = w2; pk.w = w3;
      *(uint4*)(krelf + (size_t)t * 8) = pk;
    } else {
      int i = idx - 152000; mpa[i] = mask[i] * PA[i];
    }
  }
}

// ---------------- fused v6: 2 batches/block, 8 waves, 2 blocks/CU, 5 barriers ----------------
__global__ __launch_bounds__(512, 4)
void fused_kernel(const float* __restrict__ x, const float* __restrict__ gm,
                  const float* __restrict__ drop, const float* __restrict__ qkv_b,
                  const u16* __restrict__ wN, const u16* __restrict__ wcN,
                  const float* __restrict__ bc, const u16* __restrict__ krelf,
                  const float* __restrict__ mpa, float* __restrict__ out) {
  __shared__ u16 smem[SMEM_U16];
  float* const Sf    = (float*)(smem + XS_O);        // 1734 f32 overlay (after GEMM)
  float* const Sf2   = (float*)(smem + SF2_O);       // 1734 f32 (rel + mpa)
  u16*   const wbf   = smem + K_O;                   // 102*32 u16 overlay (after merged)
  float* const dropl = (float*)(smem + DR_O);        // 102 f32

  const int tid = threadIdx.x;
  const int blk = blockIdx.x;
  const int lane = tid & 63;
  const int l31 = lane & 31;
  const int lh = lane >> 5;
  const int wv = tid >> 6;

  // ---- prefetch: drop (1 reg) + gm C-fragments (16 regs, QK^T C-init layout) ----
  float drv = 0.f;
  if (tid < 102) drv = drop[(size_t)blk * 102 + tid];
  float gm16[16];
  {
    const float* gmw = gm + (size_t)blk * 1734 + wv * 289;
#pragma unroll
    for (int g = 0; g < 16; ++g) {
      int I = (g & 3) + 8 * (g >> 2) + 4 * lh;
      gm16[g] = (wv < 6 && I < 17 && l31 < 17) ? gmw[I * 17 + l31] : 0.f;
    }
  }

  // ---- stage x -> LDS bf16 [34][200] ----
  const float* xb = x + (size_t)blk * 34 * 192;
  for (int idx = tid; idx < 1632; idx += 512) {
    int row = idx / 48, k4 = (idx - row * 48) * 4;
    float4 v = *(const float4*)(xb + row * 192 + k4);
    u16 p[4] = {f2b(v.x), f2b(v.y), f2b(v.z), f2b(v.w)};
    *(uint2*)(smem + XS_O + row * 200 + k4) = *(uint2*)p;
  }
  bar_lgkm();

  const int lrow = tid & 15, lg = (tid >> 4) & 3, kgrp = lg * 8;

  // ---- qkv GEMM: 36 N-tiles of 16 cols across 8 waves; B-frags reg-resident,
  //      reused over 3 M-tiles; no barriers. A-rows >=34 are garbage -> discarded ----
  for (int N = wv; N < 36; N += 8) {
    const int c0 = N * 16;
    const int which = c0 / 192;
    const int hd = c0 - which * 192;
    const int h = hd >> 6;
    const int d = (hd & 63) + lrow;
    const int c = c0 + lrow;
    const u16* wB = wN + (size_t)c * 192;
    short8 bfr[6];
#pragma unroll
    for (int kk = 0; kk < 6; ++kk)
      bfr[kk] = *(const short8*)(wB + kk * 32 + kgrp);
    const float bias = qkv_b[c];
    const float scale = which ? 1.0f : 0.125f;
#pragma unroll
    for (int m = 0; m < 3; ++m) {
      f32x4 acc = {};
#pragma unroll
      for (int kk = 0; kk < 6; ++kk) {
        short8 a = *(const short8*)(smem + XS_O + (m * 16 + lrow) * 200 + kk * 32 + kgrp);
        acc = __builtin_amdgcn_mfma_f32_16x16x32_bf16(a, bfr[kk], acc, 0, 0, 0);
      }
#pragma unroll
      for (int j = 0; j < 4; ++j) {
        int r = m * 16 + lg * 4 + j;
        if (r < 34) {
          int bi = r >= 17 ? 1 : 0, I = r - bi * 17;
          int slot = bi * 3 + h;
          u16 val = f2b((acc[j] + bias) * scale);
          if (which == 0)      smem[Q_O + slot * 1096 + I * 64 + (d ^ ((I & 7) << 3))] = val;
          else if (which == 1) smem[K_O + slot * 1088 + I * 64 + (d ^ ((I & 7) << 3))] = val;
          else                 smem[V_O + slot * 1088 + I * 64 + d] = val;
        }
      }
    }
  }
  bar_lgkm();   // q/k/v complete; x dead -> Sf may overlay

  const int rowc = l31 < 16 ? l31 : 16;

  // ==== MERGED phase: QK^T (waves 0-5, -> Sf) || rel+mpa (all waves, -> Sf2)
  //      || dropl park. Disjoint output buffers -> no ordering needed. ====
  if (wv < 6) {
    int bh = wv;
    const u16* qb = smem + Q_O + bh * 1096;
    const u16* kb = smem + K_O + bh * 1088;
    const int swr = (rowc & 7) << 3;
    f32x16 acc;
#pragma unroll
    for (int g = 0; g < 16; ++g) acc[g] = gm16[g];
#pragma unroll
    for (int ks = 0; ks < 4; ++ks) {
      int off = (ks * 16 + lh * 8) ^ swr;
      short8 afr = *(const short8*)(qb + rowc * 64 + off);
      short8 bfr = *(const short8*)(kb + rowc * 64 + off);
      acc = __builtin_amdgcn_mfma_f32_32x32x16_bf16(afr, bfr, acc, 0, 0, 0);
    }
    if (l31 < 17) {
      float* Sb = Sf + bh * 289 + l31;
#pragma unroll
      for (int g = 0; g < 16; ++g) {
        int I = (g & 3) + 8 * (g >> 2) + 4 * lh;
        if (I < 17) Sb[I * 17] = acc[g];
      }
    }
  }
  for (int I = wv; I < 17; I += 8) {
    int bhA = l31 < 6 ? l31 : 5;
    const u16* qb = smem + Q_O + bhA * 1096 + I * 64;
    const int swz = (I & 7) << 3;
    float mpav = (l31 < 17) ? mpa[I * 17 + l31] : 0.f;
    f32x16 acc = {};
#pragma unroll
    for (int ks = 0; ks < 4; ++ks) {
      short8 afr = *(const short8*)(qb + ((ks * 16 + lh * 8) ^ swz));
      short8 bfr = *(const short8*)(krelf + ((size_t)(I * 4 + ks) * 64 + lane) * 8);
      acc = __builtin_amdgcn_mfma_f32_32x32x16_bf16(afr, bfr, acc, 0, 0, 0);
    }
    if (l31 < 17) {
#pragma unroll
      for (int g = 0; g < 16; ++g) {
        int bh = (g & 3) + 8 * (g >> 2) + 4 * lh;
        if (bh < 6) Sf2[bh * 289 + I * 17 + l31] = acc[g] + mpav;
      }
    }
  }
  if (tid < 102) dropl[tid] = drv;
  bar_lgkm();   // S complete; k dead -> wbf may overlay

  // ---- softmax + dropout renorm -> wbf; 4 threads/row (408 threads),
  //      cols J = sub + 4i, reductions via shfl_xor width 4 ----
  if (tid < 408) {
    int r = tid >> 2, sub = tid & 3;
    int bh = r / 17, I = r - bh * 17;
    const float* Srow  = Sf  + bh * 289 + I * 17;
    const float* S2row = Sf2 + bh * 289 + I * 17;
    float lv[5];
    float mx = -3.4e38f;
#pragma unroll
    for (int i = 0; i < 5; ++i) {
      int J = sub + 4 * i;
      float v = -3.4e38f;
      if (J < 17) v = Srow[J] + S2row[J];
      lv[i] = v;
      mx = fmaxf(mx, v);
    }
    mx = fmaxf(mx, __shfl_xor(mx, 1, 4));
    mx = fmaxf(mx, __shfl_xor(mx, 2, 4));
    float s1 = 0.f;
#pragma unroll
    for (int i = 0; i < 5; ++i) {
      int J = sub + 4 * i;
      float e = 0.f;
      if (J < 17) e = __expf(lv[i] - mx);
      lv[i] = e; s1 += e;
    }
    s1 += __shfl_xor(s1, 1, 4);
    s1 += __shfl_xor(s1, 2, 4);
    float inv1 = 1.0f / s1, s2 = 0.f;
#pragma unroll
    for (int i = 0; i < 5; ++i) {
      int J = sub + 4 * i;
      float w2 = 0.f;
      if (J < 17) w2 = lv[i] * inv1 * dropl[bh * 17 + J];
      lv[i] = w2; s2 += w2;
    }
    s2 += __shfl_xor(s2, 1, 4);
    s2 += __shfl_xor(s2, 2, 4);
    float inv2 = 1.0f / (s2 + 1e-8f);
    u16* wr = wbf + r * 32;
    int swz = (I & 3) << 3;   // u16-unit swizzle, matches PV read
#pragma unroll
    for (int i = 0; i < 8; ++i) {
      int J = sub + 4 * i;
      u16 val = 0;
      if (J < 17) val = f2b(lv[i] * inv2);
      wr[J ^ swz] = val;
    }
  }
  bar_lgkm();

  // ---- PV -> ao (overlays dead Sf at XS_O, [34][200]); nt-tiles serialized;
  //      v B-frags assembled via conflict-free ds_read_u16 from [17][64] slots ----
  if (wv < 6) {
    int bh = wv;
    const u16* wb = wbf + (bh * 17 + rowc) * 32;
    int sw = (rowc & 3) << 3;   // u16 units
    short8 wa0 = *(const short8*)(wb + ((lh * 8) ^ sw));
    short8 wa1 = *(const short8*)(wb + ((lh * 8 + 16) ^ sw));
    int bi = bh >= 3 ? 1 : 0, h = bh - bi * 3;
    const u16* vb = smem + V_O + bh * 1088;
#pragma unroll
    for (int nt = 0; nt < 2; ++nt) {
      int d = nt * 32 + l31;
      short8 v0;
#pragma unroll
      for (int i = 0; i < 8; ++i) v0[i] = (short)vb[(lh * 8 + i) * 64 + d];
      f32x16 acc = {};
      acc = __builtin_amdgcn_mfma_f32_32x32x16_bf16(wa0, v0, acc, 0, 0, 0);
      short8 v1 = {};
      if (lh == 0) v1[0] = (short)vb[16 * 64 + d];
      acc = __builtin_amdgcn_mfma_f32_32x32x16_bf16(wa1, v1, acc, 0, 0, 0);
#pragma unroll
      for (int g = 0; g < 16; ++g) {
        int I = (g & 3) + 8 * (g >> 2) + 4 * lh;
        if (I < 17) smem[XS_O + (bi * 17 + I) * 200 + h * 64 + d] = f2b(acc[g]);
      }
    }
  }
  bar_lgkm();

  // ---- out-proj: 12 n-tiles across 8 waves; B-frags reg-resident over 3 M-tiles.
  //      A = ao at XS_O; rows >=34 read in-bounds garbage -> discarded ----
  float* outb = out + (size_t)blk * 34 * 192;
  for (int n = wv; n < 12; n += 8) {
    const int nc = n * 16 + lrow;
    short8 bfr[6];
#pragma unroll
    for (int kk = 0; kk < 6; ++kk)
      bfr[kk] = *(const short8*)(wcN + (size_t)nc * 192 + kk * 32 + kgrp);
    const float bias = bc[nc];
#pragma unroll
    for (int m = 0; m < 3; ++m) {
      f32x4 acc = {};
#pragma unroll
      for (int kk = 0; kk < 6; ++kk) {
        short8 a = *(const short8*)(smem + XS_O + (m * 16 + lrow) * 200 + kk * 32 + kgrp);
        acc = __builtin_amdgcn_mfma_f32_16x16x32_bf16(a, bfr[kk], acc, 0, 0, 0);
      }
#pragma unroll
      for (int j = 0; j < 4; ++j) {
        int r = m * 16 + lg * 4 + j;
        if (r < 34) outb[(size_t)r * 192 + nc] = acc[j] + bias;
      }
    }
  }
}

extern "C" void kernel_launch(void* const* d_in, const int* in_sizes, int n_in,
                              void* d_out, int out_size, void* d_ws, size_t ws_size,
                              hipStream_t stream) {
  const float* x    = (const float*)d_in[0];
  const float* mask = (const float*)d_in[1];
  const float* gm   = (const float*)d_in[2];
  const float* drop = (const float*)d_in[3];
  const float* qkvw = (const float*)d_in[4];
  const float* qkvb = (const float*)d_in[5];
  const float* attw = (const float*)d_in[6];
  const float* attb = (const float*)d_in[7];
  const float* krel = (const float*)d_in[8];
  const float* krd  = (const float*)d_in[9];
  const float* PA   = (const float*)d_in[10];
  const float* nn1w = (const float*)d_in[11];
  const float* nn1b = (const float*)d_in[12];
  char* ws = (char*)d_ws;
  float* out = (float*)d_out;

  prep_kernel<<<600, 256, 0, stream>>>(qkvw, attw, attb, nn1w, nn1b, krel, krd, mask, PA, ws);

  const u16* wN    = (const u16*)(ws + WN_OFF);
  const u16* wcN   = (const u16*)(ws + WCN_OFF);
  const float* bc  = (const float*)(ws + BC_OFF);
  const u16* krelf = (const u16*)(ws + KRELF_OFF);
  const float* mpa = (const float*)(ws + MPA_OFF);

  fused_kernel<<<NB_TOT / 2, 512, 0, stream>>>(x, gm, drop, qkvb, wN, wcN, bc, krelf, mpa, out);
}

// Round 5
// 187.921 us; speedup vs baseline: 1.4321x; 1.0010x over previous
//
#include <hip/hip_runtime.h>

typedef __attribute__((ext_vector_type(8))) short short8;
typedef __attribute__((ext_vector_type(4))) float f32x4;
typedef __attribute__((ext_vector_type(16))) float f32x16;
typedef unsigned short u16;
typedef unsigned int u32;

#define NB_TOT 8192
#define DIM 192

// ws byte offsets (prep outputs only)
#define WN_OFF    0          // [576][192] bf16 qkv_w (n-major)
#define WCN_OFF   221184     // [192][192] bf16 nn1_w@attn_w (n-major)
#define BC_OFF    294912     // [192] f32
#define KRELF_OFF 295680     // [17][4][64][8] bf16 rel B-frags
#define MPA_OFF   365312     // [289] f32 mask*PA

// fused LDS (u16 units), block = 2 batches (34 rows, 6 bh), 512 threads (8 waves)
// 53,152 B -> alloc 53,248; x3 = 159,744 fits => 3 blocks/CU (v5-proven threshold):
//   XSF @ 0     : x[34][200] bf16 (GEMM A-rows >=34 read in-bounds garbage, discarded)
//                 overlay1: Sf f32[1734] @ 0 + Sf2 f32[1734] @ u16 3468 (born at
//                           merged phase after x dead; dead after softmax)
//                 overlay2: ao [34][200] (born at PV, read by out-proj)
//   K   @ 6944  : k slots [bh][17][64] XOR-swizzled (col ^ ((row&7)<<3)), stride 1088
//                 overlay: wbf u16[102*32] + dropl f32[102] (k dead after merged phase)
//   V   @ 13472 : v slots [bh][17][64] plain, stride 1088
//   Q   @ 20000 : q slots [bh][17][64] XOR-swizzled, stride 1096 (8-u16 inter-slot pad)
#define XS_O  0
#define SF2_U16 3468
#define K_O   6944
#define V_O   13472
#define Q_O   20000
#define SMEM_U16 26576

__device__ __forceinline__ u16 f2b(float f) {
  u32 u = __float_as_uint(f);
  u32 r = u + 0x7FFFu + ((u >> 16) & 1u);  // RNE
  return (u16)(r >> 16);
}

// LDS-only barrier (global ops have register data-deps; final stores need no drain)
__device__ __forceinline__ void bar_lgkm() {
  asm volatile("s_waitcnt lgkmcnt(0)" ::: "memory");
  __builtin_amdgcn_s_barrier();
  asm volatile("" ::: "memory");
}

__global__ void prep_kernel(const float* __restrict__ qkv_w,
                            const float* __restrict__ attn_w,
                            const float* __restrict__ attn_b,
                            const float* __restrict__ nn1_w,
                            const float* __restrict__ nn1_b,
                            const float* __restrict__ key_rel,
                            const float* __restrict__ krd,
                            const float* __restrict__ mask,
                            const float* __restrict__ PA,
                            char* __restrict__ ws) {
  u16* wN    = (u16*)(ws + WN_OFF);
  u16* wcN   = (u16*)(ws + WCN_OFF);
  float* bc  = (float*)(ws + BC_OFF);
  u16* krelf = (u16*)(ws + KRELF_OFF);
  float* mpa = (float*)(ws + MPA_OFF);
  for (int idx = blockIdx.x * 256 + threadIdx.x; idx < 152289; idx += gridDim.x * 256) {
    if (idx < 110592) {
      wN[idx] = f2b(qkv_w[idx]);
    } else if (idx < 147456) {
      int t2 = idx - 110592; int n = t2 / 192, k = t2 - n * 192;
      float a = 0.f;
      for (int t = 0; t < 192; ++t) a = fmaf(nn1_w[n * 192 + t], attn_w[t * 192 + k], a);
      wcN[n * 192 + k] = f2b(a);
    } else if (idx < 147648) {
      int n = idx - 147456; float a = nn1_b[n];
      for (int t = 0; t < 192; ++t) a = fmaf(nn1_w[n * 192 + t], attn_b[t], a);
      bc[n] = a;
    } else if (idx < 152000) {
      int t = idx - 147648;              // ((I*4+ks)*64 + lane)
      int lane = t & 63, ks = (t >> 6) & 3, I = t >> 8;
      int J = lane & 31;
      int d0 = ks * 16 + (lane >> 5) * 8;
      u16 vals[8];
#pragma unroll
      for (int i = 0; i < 8; ++i) {
        float v = 0.f;
        if (J <= 16) {
          if (J == I) v = krd[d0 + i];
          else { int tt = 17 * I + J; int p = tt - tt / 18 - 1; v = key_rel[p * 64 + d0 + i]; }
        }
        vals[i] = f2b(v);
      }
      u32 w0 = vals[0] | ((u32)vals[1] << 16), w1 = vals[2] | ((u32)vals[3] << 16);
      u32 w2 = vals[4] | ((u32)vals[5] << 16), w3 = vals[6] | ((u32)vals[7] << 16);
      uint4 pk; pk.x = w0; pk.y = w1; pk.z = w2; pk.w = w3;
      *(uint4*)(krelf + (size_t)t * 8) = pk;
    } else {
      int i = idx - 152000; mpa[i] = mask[i] * PA[i];
    }
  }
}

// ---------------- fused v7: v6 compute, 53,248 B LDS => 3 blocks/CU ----------------
__global__ __launch_bounds__(512, 4)
void fused_kernel(const float* __restrict__ x, const float* __restrict__ gm,
                  const float* __restrict__ drop, const float* __restrict__ qkv_b,
                  const u16* __restrict__ wN, const u16* __restrict__ wcN,
                  const float* __restrict__ bc, const u16* __restrict__ krelf,
                  const float* __restrict__ mpa, float* __restrict__ out) {
  __shared__ u16 smem[SMEM_U16];
  float* const Sf    = (float*)(smem + XS_O);        // 1734 f32 overlay (after GEMM)
  float* const Sf2   = (float*)(smem + SF2_U16);     // 1734 f32 (rel + mpa), same overlay
  u16*   const wbf   = smem + K_O;                   // 102*32 u16 overlay (after merged)
  float* const dropl = (float*)(smem + K_O + 3264);  // 102 f32, after wbf in dead-K

  const int tid = threadIdx.x;
  const int blk = blockIdx.x;
  const int lane = tid & 63;
  const int l31 = lane & 31;
  const int lh = lane >> 5;
  const int wv = tid >> 6;

  // ---- prefetch: drop (1 reg) + gm C-fragments (16 regs, QK^T C-init layout) ----
  float drv = 0.f;
  if (tid < 102) drv = drop[(size_t)blk * 102 + tid];
  float gm16[16];
  {
    const float* gmw = gm + (size_t)blk * 1734 + wv * 289;
#pragma unroll
    for (int g = 0; g < 16; ++g) {
      int I = (g & 3) + 8 * (g >> 2) + 4 * lh;
      gm16[g] = (wv < 6 && I < 17 && l31 < 17) ? gmw[I * 17 + l31] : 0.f;
    }
  }

  // ---- stage x -> LDS bf16 [34][200] ----
  const float* xb = x + (size_t)blk * 34 * 192;
  for (int idx = tid; idx < 1632; idx += 512) {
    int row = idx / 48, k4 = (idx - row * 48) * 4;
    float4 v = *(const float4*)(xb + row * 192 + k4);
    u16 p[4] = {f2b(v.x), f2b(v.y), f2b(v.z), f2b(v.w)};
    *(uint2*)(smem + XS_O + row * 200 + k4) = *(uint2*)p;
  }
  bar_lgkm();

  const int lrow = tid & 15, lg = (tid >> 4) & 3, kgrp = lg * 8;

  // ---- qkv GEMM: 36 N-tiles of 16 cols across 8 waves; B-frags reg-resident,
  //      reused over 3 M-tiles; no barriers. A-rows >=34 read in-bounds garbage
  //      (lands in K/V regions mid-write -- discarded at store) ----
  for (int N = wv; N < 36; N += 8) {
    const int c0 = N * 16;
    const int which = c0 / 192;
    const int hd = c0 - which * 192;
    const int h = hd >> 6;
    const int d = (hd & 63) + lrow;
    const int c = c0 + lrow;
    const u16* wB = wN + (size_t)c * 192;
    short8 bfr[6];
#pragma unroll
    for (int kk = 0; kk < 6; ++kk)
      bfr[kk] = *(const short8*)(wB + kk * 32 + kgrp);
    const float bias = qkv_b[c];
    const float scale = which ? 1.0f : 0.125f;
#pragma unroll
    for (int m = 0; m < 3; ++m) {
      f32x4 acc = {};
#pragma unroll
      for (int kk = 0; kk < 6; ++kk) {
        short8 a = *(const short8*)(smem + XS_O + (m * 16 + lrow) * 200 + kk * 32 + kgrp);
        acc = __builtin_amdgcn_mfma_f32_16x16x32_bf16(a, bfr[kk], acc, 0, 0, 0);
      }
#pragma unroll
      for (int j = 0; j < 4; ++j) {
        int r = m * 16 + lg * 4 + j;
        if (r < 34) {
          int bi = r >= 17 ? 1 : 0, I = r - bi * 17;
          int slot = bi * 3 + h;
          u16 val = f2b((acc[j] + bias) * scale);
          if (which == 0)      smem[Q_O + slot * 1096 + I * 64 + (d ^ ((I & 7) << 3))] = val;
          else if (which == 1) smem[K_O + slot * 1088 + I * 64 + (d ^ ((I & 7) << 3))] = val;
          else                 smem[V_O + slot * 1088 + I * 64 + d] = val;
        }
      }
    }
  }
  bar_lgkm();   // q/k/v complete; x dead -> Sf/Sf2 may overlay

  const int rowc = l31 < 16 ? l31 : 16;

  // ==== MERGED phase: QK^T (waves 0-5, -> Sf) || rel+mpa (all waves, -> Sf2)
  //      || dropl park. Disjoint output buffers -> no ordering needed. ====
  if (wv < 6) {
    int bh = wv;
    const u16* qb = smem + Q_O + bh * 1096;
    const u16* kb = smem + K_O + bh * 1088;
    const int swr = (rowc & 7) << 3;
    f32x16 acc;
#pragma unroll
    for (int g = 0; g < 16; ++g) acc[g] = gm16[g];
#pragma unroll
    for (int ks = 0; ks < 4; ++ks) {
      int off = (ks * 16 + lh * 8) ^ swr;
      short8 afr = *(const short8*)(qb + rowc * 64 + off);
      short8 bfr = *(const short8*)(kb + rowc * 64 + off);
      acc = __builtin_amdgcn_mfma_f32_32x32x16_bf16(afr, bfr, acc, 0, 0, 0);
    }
    if (l31 < 17) {
      float* Sb = Sf + bh * 289 + l31;
#pragma unroll
      for (int g = 0; g < 16; ++g) {
        int I = (g & 3) + 8 * (g >> 2) + 4 * lh;
        if (I < 17) Sb[I * 17] = acc[g];
      }
    }
  }
  for (int I = wv; I < 17; I += 8) {
    int bhA = l31 < 6 ? l31 : 5;
    const u16* qb = smem + Q_O + bhA * 1096 + I * 64;
    const int swz = (I & 7) << 3;
    float mpav = (l31 < 17) ? mpa[I * 17 + l31] : 0.f;
    f32x16 acc = {};
#pragma unroll
    for (int ks = 0; ks < 4; ++ks) {
      short8 afr = *(const short8*)(qb + ((ks * 16 + lh * 8) ^ swz));
      short8 bfr = *(const short8*)(krelf + ((size_t)(I * 4 + ks) * 64 + lane) * 8);
      acc = __builtin_amdgcn_mfma_f32_32x32x16_bf16(afr, bfr, acc, 0, 0, 0);
    }
    if (l31 < 17) {
#pragma unroll
      for (int g = 0; g < 16; ++g) {
        int bh = (g & 3) + 8 * (g >> 2) + 4 * lh;
        if (bh < 6) Sf2[bh * 289 + I * 17 + l31] = acc[g] + mpav;
      }
    }
  }
  if (tid < 102) dropl[tid] = drv;
  bar_lgkm();   // S complete; k dead -> wbf may overlay

  // ---- softmax + dropout renorm -> wbf; 4 threads/row (408 threads),
  //      cols J = sub + 4i, reductions via shfl_xor width 4 ----
  if (tid < 408) {
    int r = tid >> 2, sub = tid & 3;
    int bh = r / 17, I = r - bh * 17;
    const float* Srow  = Sf  + bh * 289 + I * 17;
    const float* S2row = Sf2 + bh * 289 + I * 17;
    float lv[5];
    float mx = -3.4e38f;
#pragma unroll
    for (int i = 0; i < 5; ++i) {
      int J = sub + 4 * i;
      float v = -3.4e38f;
      if (J < 17) v = Srow[J] + S2row[J];
      lv[i] = v;
      mx = fmaxf(mx, v);
    }
    mx = fmaxf(mx, __shfl_xor(mx, 1, 4));
    mx = fmaxf(mx, __shfl_xor(mx, 2, 4));
    float s1 = 0.f;
#pragma unroll
    for (int i = 0; i < 5; ++i) {
      int J = sub + 4 * i;
      float e = 0.f;
      if (J < 17) e = __expf(lv[i] - mx);
      lv[i] = e; s1 += e;
    }
    s1 += __shfl_xor(s1, 1, 4);
    s1 += __shfl_xor(s1, 2, 4);
    float inv1 = 1.0f / s1, s2 = 0.f;
#pragma unroll
    for (int i = 0; i < 5; ++i) {
      int J = sub + 4 * i;
      float w2 = 0.f;
      if (J < 17) w2 = lv[i] * inv1 * dropl[bh * 17 + J];
      lv[i] = w2; s2 += w2;
    }
    s2 += __shfl_xor(s2, 1, 4);
    s2 += __shfl_xor(s2, 2, 4);
    float inv2 = 1.0f / (s2 + 1e-8f);
    u16* wr = wbf + r * 32;
    int swz = (I & 3) << 3;   // u16-unit swizzle, matches PV read
#pragma unroll
    for (int i = 0; i < 8; ++i) {
      int J = sub + 4 * i;
      u16 val = 0;
      if (J < 17) val = f2b(lv[i] * inv2);
      wr[J ^ swz] = val;
    }
  }
  bar_lgkm();

  // ---- PV -> ao (overlays dead Sf/Sf2 at XS_O, [34][200]); nt-tiles serialized;
  //      v B-frags assembled via conflict-free ds_read_u16 from [17][64] slots ----
  if (wv < 6) {
    int bh = wv;
    const u16* wb = wbf + (bh * 17 + rowc) * 32;
    int sw = (rowc & 3) << 3;   // u16 units
    short8 wa0 = *(const short8*)(wb + ((lh * 8) ^ sw));
    short8 wa1 = *(const short8*)(wb + ((lh * 8 + 16) ^ sw));
    int bi = bh >= 3 ? 1 : 0, h = bh - bi * 3;
    const u16* vb = smem + V_O + bh * 1088;
#pragma unroll
    for (int nt = 0; nt < 2; ++nt) {
      int d = nt * 32 + l31;
      short8 v0;
#pragma unroll
      for (int i = 0; i < 8; ++i) v0[i] = (short)vb[(lh * 8 + i) * 64 + d];
      f32x16 acc = {};
      acc = __builtin_amdgcn_mfma_f32_32x32x16_bf16(wa0, v0, acc, 0, 0, 0);
      short8 v1 = {};
      if (lh == 0) v1[0] = (short)vb[16 * 64 + d];
      acc = __builtin_amdgcn_mfma_f32_32x32x16_bf16(wa1, v1, acc, 0, 0, 0);
#pragma unroll
      for (int g = 0; g < 16; ++g) {
        int I = (g & 3) + 8 * (g >> 2) + 4 * lh;
        if (I < 17) smem[XS_O + (bi * 17 + I) * 200 + h * 64 + d] = f2b(acc[g]);
      }
    }
  }
  bar_lgkm();

  // ---- out-proj: 12 n-tiles across 8 waves; B-frags reg-resident over 3 M-tiles.
  //      A = ao at XS_O; rows >=34 read in-bounds garbage -> discarded ----
  float* outb = out + (size_t)blk * 34 * 192;
  for (int n = wv; n < 12; n += 8) {
    const int nc = n * 16 + lrow;
    short8 bfr[6];
#pragma unroll
    for (int kk = 0; kk < 6; ++kk)
      bfr[kk] = *(const short8*)(wcN + (size_t)nc * 192 + kk * 32 + kgrp);
    const float bias = bc[nc];
#pragma unroll
    for (int m = 0; m < 3; ++m) {
      f32x4 acc = {};
#pragma unroll
      for (int kk = 0; kk < 6; ++kk) {
        short8 a = *(const short8*)(smem + XS_O + (m * 16 + lrow) * 200 + kk * 32 + kgrp);
        acc = __builtin_amdgcn_mfma_f32_16x16x32_bf16(a, bfr[kk], acc, 0, 0, 0);
      }
#pragma unroll
      for (int j = 0; j < 4; ++j) {
        int r = m * 16 + lg * 4 + j;
        if (r < 34) outb[(size_t)r * 192 + nc] = acc[j] + bias;
      }
    }
  }
}

extern "C" void kernel_launch(void* const* d_in, const int* in_sizes, int n_in,
                              void* d_out, int out_size, void* d_ws, size_t ws_size,
                              hipStream_t stream) {
  const float* x    = (const float*)d_in[0];
  const float* mask = (const float*)d_in[1];
  const float* gm   = (const float*)d_in[2];
  const float* drop = (const float*)d_in[3];
  const float* qkvw = (const float*)d_in[4];
  const float* qkvb = (const float*)d_in[5];
  const float* attw = (const float*)d_in[6];
  const float* attb = (const float*)d_in[7];
  const float* krel = (const float*)d_in[8];
  const float* krd  = (const float*)d_in[9];
  const float* PA   = (const float*)d_in[10];
  const float* nn1w = (const float*)d_in[11];
  const float* nn1b = (const float*)d_in[12];
  char* ws = (char*)d_ws;
  float* out = (float*)d_out;

  prep_kernel<<<600, 256, 0, stream>>>(qkvw, attw, attb, nn1w, nn1b, krel, krd, mask, PA, ws);

  const u16* wN    = (const u16*)(ws + WN_OFF);
  const u16* wcN   = (const u16*)(ws + WCN_OFF);
  const float* bc  = (const float*)(ws + BC_OFF);
  const u16* krelf = (const u16*)(ws + KRELF_OFF);
  const float* mpa = (const float*)(ws + MPA_OFF);

  fused_kernel<<<NB_TOT / 2, 512, 0, stream>>>(x, gm, drop, qkvb, wN, wcN, bc, krelf, mpa, out);
}